// Round 31
// baseline (135.756 us; speedup 1.0000x reference)
//
#include <hip/hip_runtime.h>

constexpr int Bn = 4, CG = 16, HH = 384, WW = 384;
constexpr int HWSZ = HH * WW;  // 147456
constexpr int COUT = 24;

typedef __attribute__((ext_vector_type(8))) short short8v;
typedef __attribute__((ext_vector_type(4))) float f32x4;

__device__ __forceinline__ unsigned short f2bf(float f) {
  unsigned u = __float_as_uint(f);
  unsigned r = (u + 0x7FFFu + ((u >> 16) & 1u)) >> 16;  // RNE
  return (unsigned short)r;
}

// ---------------------------------------------------------------------------
// wtrans2: bf16 weights, K reordered as (tap-pair, ic):
// k = s*32 + kg*8 + j ; tap = 2s + (kg>>1) ; ic = (kg&1)*8 + j.
// Wbf2[oc][k] = Wc[(oc*16+ic)*9 + tap] (0 for oc>=24 or tap>=9).
// ---------------------------------------------------------------------------
__global__ void wtrans2_kernel(const float* __restrict__ Wc,
                               unsigned short* __restrict__ Wbf2) {
  int i = blockIdx.x * 256 + threadIdx.x;
  if (i < 32 * 160) {
    int oc = i / 160, k = i % 160;
    int s = k >> 5, kg = (k >> 3) & 3, j = k & 7;
    int tap = 2 * s + (kg >> 1);
    int ic = (kg & 1) * 8 + j;
    float v = (oc < 24 && tap < 9) ? Wc[(oc * 16 + ic) * 9 + tap] : 0.f;
    Wbf2[i] = f2bf(v);
  }
}

// ---------------------------------------------------------------------------
// Implicit-GEMM MFMA conv (round-30 structure) with 8-ic PACKED staging:
// one task per (yl, ich, xl) loads 8 ic-planes and emits ONE ds_write_b128
// (tasks 5440 -> 680, 21.25 -> 2.7 passes/thread, addr calc amortized 8x,
// 8 loads in flight per task). Same values/layout -> bit-identical output.
// Coalesced offT3 stores via 8KB SB staging (round-30, validated).
// ---------------------------------------------------------------------------
__global__ __launch_bounds__(256) void convmfma5_kernel(
    const float* __restrict__ g, const unsigned short* __restrict__ Wbf2,
    const float* __restrict__ bc, float* __restrict__ out_off,
    float* __restrict__ affc, float* __restrict__ offT3f) {
  __shared__ unsigned short Gt[10 * 2 * 34 * 8];  // 10.6 KB
  __shared__ float SB[16 * 4 * 8 * 4];            //  8.0 KB
  int bi = blockIdx.x;
  int bx = (bi % 12) * 32;
  int by = ((bi / 12) % 48) * 8;
  int b = bi / 576;
  const float* gb = g + (size_t)b * CG * HWSZ;

  int t = threadIdx.x;
  // Packed staging: task = (yl, ich, xl); 8 ic loads -> 1 ds_write_b128.
  for (int e = t; e < 10 * 2 * 34; e += 256) {
    int xl = e % 34;
    int rem = e / 34;  // 0..19
    int ich = rem & 1;
    int yl = rem >> 1;
    int gy = by - 1 + yl, gx = bx - 1 + xl;
    bool ok = (gy >= 0) && (gy < HH) && (gx >= 0) && (gx < WW);
    const float* gp = gb + (ich * 8) * HWSZ + gy * WW + gx;
    unsigned short w[8];
#pragma unroll
    for (int q = 0; q < 8; ++q)
      w[q] = ok ? f2bf(gp[q * HWSZ]) : (unsigned short)0;
    *(uint4*)&Gt[((yl * 2 + ich) * 34 + xl) * 8] = *(const uint4*)w;
  }
  __syncthreads();

  int lane = t & 63, wv = t >> 6;
  int kg = lane >> 4, arow = lane & 15;
  int ich = kg & 1, tsel = kg >> 1;

  // Preload A fragments (weights): 10 x 16B.
  short8v a0[5], a1[5];
#pragma unroll
  for (int s = 0; s < 5; ++s) {
    a0[s] = *(const short8v*)&Wbf2[arow * 160 + s * 32 + kg * 8];
    a1[s] = *(const short8v*)&Wbf2[(16 + arow) * 160 + s * 32 + kg * 8];
  }

  float* ob = out_off + (size_t)b * 18 * HWSZ;
  float* ab = affc + (size_t)b * 8 * HWSZ;
  float* o3b = offT3f + (size_t)b * 16 * 48 * 384 * 4;
  int rbase = 4 * kg;

#pragma unroll
  for (int gi4 = 0; gi4 < 4; ++gi4) {
    int gi = wv * 4 + gi4;
    int row = gi >> 1, xg = (gi & 1) * 16;
    int lx = xg + arow;

    f32x4 acc0 = {0.f, 0.f, 0.f, 0.f};
    f32x4 acc1 = {0.f, 0.f, 0.f, 0.f};
#pragma unroll
    for (int s = 0; s < 5; ++s) {
      int tp = 2 * s + tsel;
      int tb = (tp > 8) ? 8 : tp;  // A rows are zero for tp==9
      int r = tb / 3, c = tb % 3;
      short8v bf_ =
          *(const short8v*)&Gt[(((row + r) * 2 + ich) * 34 + lx + c) * 8];
      acc0 = __builtin_amdgcn_mfma_f32_16x16x32_bf16(a0[s], bf_, acc0, 0, 0, 0);
      acc1 = __builtin_amdgcn_mfma_f32_16x16x32_bf16(a1[s], bf_, acc1, 0, 0, 0);
    }

    int colg = bx + lx;
    int y = by + row;
    int p = y * WW + colg;
    int ml = (colg >> 3) & 3, j = colg & 7;

#pragma unroll
    for (int reg = 0; reg < 4; ++reg) {
      int oc = rbase + reg;  // 0..15
      float v = acc0[reg] + bc[oc];
      if (oc < 8) {
        ob[oc * HWSZ + p] = v;
      } else {
        ob[(oc + 2) * HWSZ + p] = v;
        int pl = oc - 8;
        int cp = pl >> 1, sel = pl & 1;
        int q = sel * 2 + (j >> 2);
        SB[(((cp * 4 + q) * 4 + ml) * 8 + row) * 4 + (j & 3)] = v;
      }
    }
    if (kg < 2) {
#pragma unroll
      for (int reg = 0; reg < 4; ++reg) {
        int oc16 = 16 + rbase + reg;  // 16..23
        float v = acc1[reg] + bc[oc16];
        ab[(oc16 - 16) * HWSZ + p] = v;
      }
    }
    if (kg == 0) {
      ob[8 * HWSZ + p] = 0.f;
      ob[9 * HWSZ + p] = 0.f;
    }
  }

  // Coalesced offT3 flush: 512 float4 = 64 chunks of 128B.
  __syncthreads();
  int mb = bx >> 3;
  for (int f = t; f < 512; f += 256) {
    int chunk = f >> 3, yy = f & 7;
    int s16 = chunk >> 2, m = chunk & 3;
    float4 v4 = *(const float4*)&SB[((s16 * 4 + m) * 8 + yy) * 4];
    size_t di = ((size_t)(s16 * 48) + mb + m) * 384 + by + yy;
    *(float4*)&o3b[di * 4] = v4;
  }
}

// ---------------------------------------------------------------------------
// Bilinear sample, zero padding — identical math to the reference (fallback).
// ---------------------------------------------------------------------------
__device__ __forceinline__ float bilin_zero(const float* __restrict__ img,
                                            float iy, float ix) {
  float y0f = floorf(iy), x0f = floorf(ix);
  float wy1 = iy - y0f, wx1 = ix - x0f;
  int y0 = (int)y0f, x0 = (int)x0f;
  float acc = 0.f;
#pragma unroll
  for (int dy = 0; dy < 2; ++dy) {
    int yc = y0 + dy;
    bool vy = (yc >= 0) && (yc <= HH - 1);
    int yi = min(max(yc, 0), HH - 1);
    float wy = dy ? wy1 : 1.f - wy1;
#pragma unroll
    for (int dx = 0; dx < 2; ++dx) {
      int xc = x0 + dx;
      bool vx = (xc >= 0) && (xc <= WW - 1);
      int xi = min(max(xc, 0), WW - 1);
      float wx = dx ? wx1 : 1.f - wx1;
      float v = img[yi * WW + xi];
      acc += v * (wy * wx) * ((vy && vx) ? 1.f : 0.f);
    }
  }
  return acc;
}

// ---------------------------------------------------------------------------
// cw for c=4..7: LDS patch for gathers + cooperative LDS staging of fea
// operands and cw4 results (unchanged).
// ---------------------------------------------------------------------------
__global__ __launch_bounds__(256, 4) void cw47h_kernel(
    const float* __restrict__ fea, const float4* __restrict__ offT3,
    float* __restrict__ cw4) {
  __shared__ float patch[64][68];   // 17.4 KB
  __shared__ float sfea[8][64][5];  // 10.2 KB
  __shared__ float scw[4][64][5];   //  5.1 KB
  int t = threadIdx.x;
  int lane = t & 63, wv = t >> 6;
  int bi = blockIdx.x;
  int Lblk = bi % 6;  bi /= 6;
  int mblk = bi % 12; bi /= 12;
  int a = bi % 8, b = bi / 8;
  int m = mblk * 4 + wv;

  const float* feab = fea + (size_t)b * 8 * HWSZ;
  const float* imgA = feab + (size_t)a * HWSZ;
  int p_base = a * 18432 + 48 * (Lblk * 64) + mblk * 4;

  int R0 = 32 * mblk - 12;
  R0 = (R0 < 0) ? 0 : (R0 > 320 ? 320 : R0);

#pragma unroll
  for (int i = 0; i < 2; ++i) {
    int L = i * 256 + t;
    int j = L >> 6, Lpl = L & 63;
    float4 v = *(const float4*)(feab + (size_t)j * HWSZ + p_base + 48 * Lpl);
    sfea[j][Lpl][0] = v.x;
    sfea[j][Lpl][1] = v.y;
    sfea[j][Lpl][2] = v.z;
    sfea[j][Lpl][3] = v.w;
  }
  {
    int row = t >> 4, colq = t & 15;
#pragma unroll
    for (int pass = 0; pass < 4; ++pass) {
      int r = pass * 16 + row;
      float4 v = *(const float4*)(imgA + (R0 + r) * WW + R0 + 4 * colq);
      *(float4*)&patch[r][4 * colq] = v;
    }
  }
  __syncthreads();

  float feaj[8];
#pragma unroll
  for (int j = 0; j < 8; ++j) feaj[j] = sfea[j][lane][wv];

  const float4* o3 = offT3 + (size_t)b * 16 * 48 * 384;
  int recoff = m * 384 + (Lblk * 64 + lane);
  float qf = (float)(8 * m);

#pragma unroll
  for (int cp = 0; cp < 4; ++cp) {
    float4 dy0 = o3[(cp * 4 + 0) * 18432 + recoff];
    float4 dy1 = o3[(cp * 4 + 1) * 18432 + recoff];
    float4 dx0 = o3[(cp * 4 + 2) * 18432 + recoff];
    float4 dx1 = o3[(cp * 4 + 3) * 18432 + recoff];
    float dyv[8] = {dy0.x, dy0.y, dy0.z, dy0.w, dy1.x, dy1.y, dy1.z, dy1.w};
    float dxv[8] = {dx0.x, dx0.y, dx0.z, dx0.w, dx1.x, dx1.y, dx1.z, dx1.w};
    float s = 0.f;
#pragma unroll
    for (int j = 0; j < 8; ++j) {
      float iy = dxv[j] + qf + (float)j;
      float ix = dyv[j] + qf + (float)j;
      float y0f = floorf(iy), x0f = floorf(ix);
      int y0 = (int)y0f, x0 = (int)x0f;
      float fy = iy - y0f, fx = ix - x0f;
      float bv;
      if (y0 >= R0 && y0 <= R0 + 62 && x0 >= R0 && x0 <= R0 + 62) {
        int ry = y0 - R0, rx = x0 - R0;
        float v00 = patch[ry][rx], v01 = patch[ry][rx + 1];
        float v10 = patch[ry + 1][rx], v11 = patch[ry + 1][rx + 1];
        float wy0 = 1.f - fy, wx0 = 1.f - fx;
        bv = v00 * (wy0 * wx0) + v01 * (wy0 * fx) + v10 * (fy * wx0) +
             v11 * (fy * fx);
      } else {
        bv = bilin_zero(imgA, iy, ix);
      }
      s += feaj[j] * bv;
    }
    scw[cp][lane][wv] = s;
  }
  __syncthreads();

  {
    int cp = t >> 6, Lpl = t & 63;
    float4 v;
    v.x = scw[cp][Lpl][0];
    v.y = scw[cp][Lpl][1];
    v.z = scw[cp][Lpl][2];
    v.w = scw[cp][Lpl][3];
    *(float4*)(cw4 + (size_t)(b * 4 + cp) * HWSZ + p_base + 48 * Lpl) = v;
  }
}

__device__ __forceinline__ float fast_tanh(float x) {
  float ax = fabsf(x);
  float e = __expf(2.f * ax);  // inf for large ax -> t = 1 (correct limit)
  float t = 1.f - 2.f * __builtin_amdgcn_rcpf(e + 1.f);
  return copysignf(t, x);
}

// ---------------------------------------------------------------------------
// Fused cw03 + epilogue: fpat LDS patch only, conf gathers global.
// ---------------------------------------------------------------------------
__global__ __launch_bounds__(256, 4) void fused5_kernel(
    const float* __restrict__ fea, const float* __restrict__ conf_img,
    const float* __restrict__ out_off, const float* __restrict__ affc,
    const float* __restrict__ cw4, const float* __restrict__ aff_scale,
    float* __restrict__ out_aff) {
  __shared__ float fpat[32][36];  // 4.6 KB
  int t = threadIdx.x;
  unsigned idx0 = blockIdx.x * 256u;
  unsigned b = idx0 / (unsigned)HWSZ;
  unsigned pb0 = idx0 % (unsigned)HWSZ;
  unsigned a = (8u * pb0) / (unsigned)HWSZ;
  unsigned r0f = 8u * pb0 - a * (unsigned)HWSZ;
  int hrf = (int)(r0f / (unsigned)WW);
  int C0 = hrf - 12;
  C0 = (C0 < 0) ? 0 : (C0 > 352 ? 352 : C0);
  C0 &= ~3;

  const float* feab = fea + (size_t)b * 8 * HWSZ;
  const float* imgA = feab + (size_t)a * HWSZ;
  const float* cimg = conf_img + (size_t)b * HWSZ;

  unsigned p = pb0 + t;
  const float* offb = out_off + (size_t)b * 18 * HWSZ;
  const float* ab = affc + (size_t)b * 8 * HWSZ;

  float feaj[8];
#pragma unroll
  for (int j = 0; j < 8; ++j) feaj[j] = feab[j * HWSZ + p];
  float abv[8];
#pragma unroll
  for (int c = 0; c < 8; ++c) abv[c] = ab[c * HWSZ + p];
  float cw4v[4];
#pragma unroll
  for (int c = 0; c < 4; ++c) cw4v[c] = cw4[((size_t)b * 4 + c) * HWSZ + p];

  {
    int rr = t >> 3, cq = t & 7;
    *(float4*)&fpat[rr][4 * cq] =
        *(const float4*)(imgA + (C0 + rr) * WW + C0 + 4 * cq);
  }
  __syncthreads();

  unsigned h = p / (unsigned)WW, wcol = p % (unsigned)WW;
  unsigned r0 = 8u * p - a * (unsigned)HWSZ;
  unsigned hr = r0 / (unsigned)WW;
  float cb = (float)hr;

  float av[8];
#pragma unroll
  for (int c = 0; c < 4; ++c) {
    const float* dyp = offb + (2 * c) * HWSZ + r0;
    const float* dxp = offb + (2 * c + 1) * HWSZ + r0;
    float4 dy0 = *(const float4*)dyp, dy1 = *(const float4*)(dyp + 4);
    float4 dx0 = *(const float4*)dxp, dx1 = *(const float4*)(dxp + 4);
    float dyv[8] = {dy0.x, dy0.y, dy0.z, dy0.w, dy1.x, dy1.y, dy1.z, dy1.w};
    float dxv[8] = {dx0.x, dx0.y, dx0.z, dx0.w, dx1.x, dx1.y, dx1.z, dx1.w};
    float s = 0.f;
#pragma unroll
    for (int j = 0; j < 8; ++j) {
      float iy = dxv[j] + cb, ix = dyv[j] + cb;
      float y0f = floorf(iy), x0f = floorf(ix);
      int y0 = (int)y0f, x0 = (int)x0f;
      float fy = iy - y0f, fx = ix - x0f;
      float bv;
      if (y0 >= C0 && y0 <= C0 + 30 && x0 >= C0 && x0 <= C0 + 30) {
        int ry = y0 - C0, rx = x0 - C0;
        float wy0 = 1.f - fy, wx0 = 1.f - fx;
        bv = fpat[ry][rx] * (wy0 * wx0) + fpat[ry][rx + 1] * (wy0 * fx) +
             fpat[ry + 1][rx] * (fy * wx0) + fpat[ry + 1][rx + 1] * (fy * fx);
      } else {
        bv = bilin_zero(imgA, iy, ix);
      }
      s += feaj[j] * bv;
    }
    av[c] = abv[c] * s;
  }
#pragma unroll
  for (int c = 4; c < 8; ++c) av[c] = abv[c] * cw4v[c - 4];

  float cf[8];
#pragma unroll
  for (int c = 0; c < 8; ++c) {
    int chy = (c < 4) ? 2 * c : 2 * c + 2;
    float dy = offb[chy * HWSZ + p];
    float dx = offb[(chy + 1) * HWSZ + p];
    cf[c] = bilin_zero(cimg, dy + (float)h, dx + (float)wcol);
  }

  float invden = __builtin_amdgcn_rcpf(aff_scale[0] + 1e-8f);
  float tv8[8];
  float asum = 0.f;
#pragma unroll
  for (int c = 0; c < 8; ++c) {
    float tv = fast_tanh(av[c]) * invden * cf[c];
    tv8[c] = tv;
    asum += fabsf(tv);
  }
  asum += 1e-4f;
  asum = fmaxf(asum, 1.f);
  float inv_asum = __builtin_amdgcn_rcpf(asum);
  float ssum = 0.f;
#pragma unroll
  for (int c = 0; c < 8; ++c) {
    tv8[c] *= inv_asum;
    ssum += tv8[c];
  }

  float v9[9];
#pragma unroll
  for (int c = 0; c < 4; ++c) v9[c] = tv8[c];
  v9[4] = 1.f - ssum;
#pragma unroll
  for (int c = 4; c < 8; ++c) v9[c + 1] = tv8[c];

  float mx = v9[0];
#pragma unroll
  for (int i = 1; i < 9; ++i) mx = fmaxf(mx, v9[i]);
  float es = 0.f;
#pragma unroll
  for (int i = 0; i < 9; ++i) {
    v9[i] = __expf(v9[i] - mx);
    es += v9[i];
  }
  float inv = __builtin_amdgcn_rcpf(es);
  float* ob = out_aff + (size_t)b * 9 * HWSZ;
#pragma unroll
  for (int i = 0; i < 9; ++i) ob[i * HWSZ + p] = v9[i] * inv;
}

extern "C" void kernel_launch(void* const* d_in, const int* in_sizes, int n_in,
                              void* d_out, int out_size, void* d_ws,
                              size_t ws_size, hipStream_t stream) {
  const float* guidance = (const float*)d_in[0];
  const float* conf_img = (const float*)d_in[1];
  const float* fea = (const float*)d_in[2];
  const float* Wc = (const float*)d_in[3];
  const float* bc = (const float*)d_in[4];
  const float* ascale = (const float*)d_in[5];

  float* out = (float*)d_out;
  float* out_off = out;                           // (4,18,384,384)
  float* out_aff = out + (size_t)Bn * 18 * HWSZ;  // (4,9,384,384) final output
  // offT3 borrows the aff region of d_out; written by convmfma5, consumed by
  // cw47h before fused5 overwrites the region. 16B-aligned.
  float* offT3f = out_aff;

  float* affc = (float*)d_ws;                        // 4*8*HW floats
  float* cw4 = affc + (size_t)Bn * 8 * HWSZ;         // 4*4*HW floats
  unsigned short* Wbf2 =
      (unsigned short*)(cw4 + (size_t)Bn * 4 * HWSZ);  // 32*160 bf16

  wtrans2_kernel<<<(32 * 160 + 255) / 256, 256, 0, stream>>>(Wc, Wbf2);

  int total = Bn * HWSZ;
  convmfma5_kernel<<<Bn * 12 * 48, 256, 0, stream>>>(guidance, Wbf2, bc,
                                                     out_off, affc, offT3f);
  cw47h_kernel<<<total / 256, 256, 0, stream>>>(fea, (const float4*)offT3f,
                                                cw4);
  fused5_kernel<<<total / 256, 256, 0, stream>>>(fea, conf_img, out_off, affc,
                                                 cw4, ascale, out_aff);
}

// Round 32
// 127.915 us; speedup vs baseline: 1.0613x; 1.0613x over previous
//
#include <hip/hip_runtime.h>

constexpr int Bn = 4, CG = 16, HH = 384, WW = 384;
constexpr int HWSZ = HH * WW;  // 147456
constexpr int COUT = 24;

typedef __attribute__((ext_vector_type(8))) short short8v;
typedef __attribute__((ext_vector_type(4))) float f32x4;

__device__ __forceinline__ unsigned short f2bf(float f) {
  unsigned u = __float_as_uint(f);
  unsigned r = (u + 0x7FFFu + ((u >> 16) & 1u)) >> 16;  // RNE
  return (unsigned short)r;
}

// XCD-aware bijective block swizzle (T1): consecutive logical blocks land on
// the same XCD's private L2. Valid when nwg % 8 == 0 (all grids here = 2304).
__device__ __forceinline__ int xcd_swz(int bid, int nwg) {
  return (bid & 7) * (nwg >> 3) + (bid >> 3);
}

// ---------------------------------------------------------------------------
// wtrans2: bf16 weights, K reordered as (tap-pair, ic):
// k = s*32 + kg*8 + j ; tap = 2s + (kg>>1) ; ic = (kg&1)*8 + j.
// Wbf2[oc][k] = Wc[(oc*16+ic)*9 + tap] (0 for oc>=24 or tap>=9).
// ---------------------------------------------------------------------------
__global__ void wtrans2_kernel(const float* __restrict__ Wc,
                               unsigned short* __restrict__ Wbf2) {
  int i = blockIdx.x * 256 + threadIdx.x;
  if (i < 32 * 160) {
    int oc = i / 160, k = i % 160;
    int s = k >> 5, kg = (k >> 3) & 3, j = k & 7;
    int tap = 2 * s + (kg >> 1);
    int ic = (kg & 1) * 8 + j;
    float v = (oc < 24 && tap < 9) ? Wc[(oc * 16 + ic) * 9 + tap] : 0.f;
    Wbf2[i] = f2bf(v);
  }
}

// ---------------------------------------------------------------------------
// Implicit-GEMM MFMA conv (round-31 structure) + XCD swizzle: y/x-adjacent
// tiles (shared halo rows, same guidance planes) now co-locate on one XCD's
// L2. 8-ic packed staging; coalesced offT3 stores via SB.
// ---------------------------------------------------------------------------
__global__ __launch_bounds__(256) void convmfma5_kernel(
    const float* __restrict__ g, const unsigned short* __restrict__ Wbf2,
    const float* __restrict__ bc, float* __restrict__ out_off,
    float* __restrict__ affc, float* __restrict__ offT3f) {
  __shared__ unsigned short Gt[10 * 2 * 34 * 8];  // 10.6 KB
  __shared__ float SB[16 * 4 * 8 * 4];            //  8.0 KB
  int bi = xcd_swz(blockIdx.x, Bn * 12 * 48);
  int bx = (bi % 12) * 32;
  int by = ((bi / 12) % 48) * 8;
  int b = bi / 576;
  const float* gb = g + (size_t)b * CG * HWSZ;

  int t = threadIdx.x;
  // Packed staging: task = (yl, ich, xl); 8 ic loads -> 1 ds_write_b128.
  for (int e = t; e < 10 * 2 * 34; e += 256) {
    int xl = e % 34;
    int rem = e / 34;  // 0..19
    int ich = rem & 1;
    int yl = rem >> 1;
    int gy = by - 1 + yl, gx = bx - 1 + xl;
    bool ok = (gy >= 0) && (gy < HH) && (gx >= 0) && (gx < WW);
    const float* gp = gb + (ich * 8) * HWSZ + gy * WW + gx;
    unsigned short w[8];
#pragma unroll
    for (int q = 0; q < 8; ++q)
      w[q] = ok ? f2bf(gp[q * HWSZ]) : (unsigned short)0;
    *(uint4*)&Gt[((yl * 2 + ich) * 34 + xl) * 8] = *(const uint4*)w;
  }
  __syncthreads();

  int lane = t & 63, wv = t >> 6;
  int kg = lane >> 4, arow = lane & 15;
  int ich = kg & 1, tsel = kg >> 1;

  // Preload A fragments (weights): 10 x 16B.
  short8v a0[5], a1[5];
#pragma unroll
  for (int s = 0; s < 5; ++s) {
    a0[s] = *(const short8v*)&Wbf2[arow * 160 + s * 32 + kg * 8];
    a1[s] = *(const short8v*)&Wbf2[(16 + arow) * 160 + s * 32 + kg * 8];
  }

  float* ob = out_off + (size_t)b * 18 * HWSZ;
  float* ab = affc + (size_t)b * 8 * HWSZ;
  float* o3b = offT3f + (size_t)b * 16 * 48 * 384 * 4;
  int rbase = 4 * kg;

#pragma unroll
  for (int gi4 = 0; gi4 < 4; ++gi4) {
    int gi = wv * 4 + gi4;
    int row = gi >> 1, xg = (gi & 1) * 16;
    int lx = xg + arow;

    f32x4 acc0 = {0.f, 0.f, 0.f, 0.f};
    f32x4 acc1 = {0.f, 0.f, 0.f, 0.f};
#pragma unroll
    for (int s = 0; s < 5; ++s) {
      int tp = 2 * s + tsel;
      int tb = (tp > 8) ? 8 : tp;  // A rows are zero for tp==9
      int r = tb / 3, c = tb % 3;
      short8v bf_ =
          *(const short8v*)&Gt[(((row + r) * 2 + ich) * 34 + lx + c) * 8];
      acc0 = __builtin_amdgcn_mfma_f32_16x16x32_bf16(a0[s], bf_, acc0, 0, 0, 0);
      acc1 = __builtin_amdgcn_mfma_f32_16x16x32_bf16(a1[s], bf_, acc1, 0, 0, 0);
    }

    int colg = bx + lx;
    int y = by + row;
    int p = y * WW + colg;
    int ml = (colg >> 3) & 3, j = colg & 7;

#pragma unroll
    for (int reg = 0; reg < 4; ++reg) {
      int oc = rbase + reg;  // 0..15
      float v = acc0[reg] + bc[oc];
      if (oc < 8) {
        ob[oc * HWSZ + p] = v;
      } else {
        ob[(oc + 2) * HWSZ + p] = v;
        int pl = oc - 8;
        int cp = pl >> 1, sel = pl & 1;
        int q = sel * 2 + (j >> 2);
        SB[(((cp * 4 + q) * 4 + ml) * 8 + row) * 4 + (j & 3)] = v;
      }
    }
    if (kg < 2) {
#pragma unroll
      for (int reg = 0; reg < 4; ++reg) {
        int oc16 = 16 + rbase + reg;  // 16..23
        float v = acc1[reg] + bc[oc16];
        ab[(oc16 - 16) * HWSZ + p] = v;
      }
    }
    if (kg == 0) {
      ob[8 * HWSZ + p] = 0.f;
      ob[9 * HWSZ + p] = 0.f;
    }
  }

  // Coalesced offT3 flush: 512 float4 = 64 chunks of 128B.
  __syncthreads();
  int mb = bx >> 3;
  for (int f = t; f < 512; f += 256) {
    int chunk = f >> 3, yy = f & 7;
    int s16 = chunk >> 2, m = chunk & 3;
    float4 v4 = *(const float4*)&SB[((s16 * 4 + m) * 8 + yy) * 4];
    size_t di = ((size_t)(s16 * 48) + mb + m) * 384 + by + yy;
    *(float4*)&o3b[di * 4] = v4;
  }
}

// ---------------------------------------------------------------------------
// Bilinear sample, zero padding — identical math to the reference (fallback).
// ---------------------------------------------------------------------------
__device__ __forceinline__ float bilin_zero(const float* __restrict__ img,
                                            float iy, float ix) {
  float y0f = floorf(iy), x0f = floorf(ix);
  float wy1 = iy - y0f, wx1 = ix - x0f;
  int y0 = (int)y0f, x0 = (int)x0f;
  float acc = 0.f;
#pragma unroll
  for (int dy = 0; dy < 2; ++dy) {
    int yc = y0 + dy;
    bool vy = (yc >= 0) && (yc <= HH - 1);
    int yi = min(max(yc, 0), HH - 1);
    float wy = dy ? wy1 : 1.f - wy1;
#pragma unroll
    for (int dx = 0; dx < 2; ++dx) {
      int xc = x0 + dx;
      bool vx = (xc >= 0) && (xc <= WW - 1);
      int xi = min(max(xc, 0), WW - 1);
      float wx = dx ? wx1 : 1.f - wx1;
      float v = img[yi * WW + xi];
      acc += v * (wy * wx) * ((vy && vx) ? 1.f : 0.f);
    }
  }
  return acc;
}

// ---------------------------------------------------------------------------
// cw for c=4..7 + XCD swizzle: the 6 Lblk-consecutive blocks (same mblk,a,b)
// read the SAME 16KB patch and offT3 rows — now co-located on one XCD's L2.
// ---------------------------------------------------------------------------
__global__ __launch_bounds__(256, 4) void cw47h_kernel(
    const float* __restrict__ fea, const float4* __restrict__ offT3,
    float* __restrict__ cw4) {
  __shared__ float patch[64][68];   // 17.4 KB
  __shared__ float sfea[8][64][5];  // 10.2 KB
  __shared__ float scw[4][64][5];   //  5.1 KB
  int t = threadIdx.x;
  int lane = t & 63, wv = t >> 6;
  int bi = xcd_swz(blockIdx.x, Bn * HWSZ / 256);
  int Lblk = bi % 6;  bi /= 6;
  int mblk = bi % 12; bi /= 12;
  int a = bi % 8, b = bi / 8;
  int m = mblk * 4 + wv;

  const float* feab = fea + (size_t)b * 8 * HWSZ;
  const float* imgA = feab + (size_t)a * HWSZ;
  int p_base = a * 18432 + 48 * (Lblk * 64) + mblk * 4;

  int R0 = 32 * mblk - 12;
  R0 = (R0 < 0) ? 0 : (R0 > 320 ? 320 : R0);

#pragma unroll
  for (int i = 0; i < 2; ++i) {
    int L = i * 256 + t;
    int j = L >> 6, Lpl = L & 63;
    float4 v = *(const float4*)(feab + (size_t)j * HWSZ + p_base + 48 * Lpl);
    sfea[j][Lpl][0] = v.x;
    sfea[j][Lpl][1] = v.y;
    sfea[j][Lpl][2] = v.z;
    sfea[j][Lpl][3] = v.w;
  }
  {
    int row = t >> 4, colq = t & 15;
#pragma unroll
    for (int pass = 0; pass < 4; ++pass) {
      int r = pass * 16 + row;
      float4 v = *(const float4*)(imgA + (R0 + r) * WW + R0 + 4 * colq);
      *(float4*)&patch[r][4 * colq] = v;
    }
  }
  __syncthreads();

  float feaj[8];
#pragma unroll
  for (int j = 0; j < 8; ++j) feaj[j] = sfea[j][lane][wv];

  const float4* o3 = offT3 + (size_t)b * 16 * 48 * 384;
  int recoff = m * 384 + (Lblk * 64 + lane);
  float qf = (float)(8 * m);

#pragma unroll
  for (int cp = 0; cp < 4; ++cp) {
    float4 dy0 = o3[(cp * 4 + 0) * 18432 + recoff];
    float4 dy1 = o3[(cp * 4 + 1) * 18432 + recoff];
    float4 dx0 = o3[(cp * 4 + 2) * 18432 + recoff];
    float4 dx1 = o3[(cp * 4 + 3) * 18432 + recoff];
    float dyv[8] = {dy0.x, dy0.y, dy0.z, dy0.w, dy1.x, dy1.y, dy1.z, dy1.w};
    float dxv[8] = {dx0.x, dx0.y, dx0.z, dx0.w, dx1.x, dx1.y, dx1.z, dx1.w};
    float s = 0.f;
#pragma unroll
    for (int j = 0; j < 8; ++j) {
      float iy = dxv[j] + qf + (float)j;
      float ix = dyv[j] + qf + (float)j;
      float y0f = floorf(iy), x0f = floorf(ix);
      int y0 = (int)y0f, x0 = (int)x0f;
      float fy = iy - y0f, fx = ix - x0f;
      float bv;
      if (y0 >= R0 && y0 <= R0 + 62 && x0 >= R0 && x0 <= R0 + 62) {
        int ry = y0 - R0, rx = x0 - R0;
        float v00 = patch[ry][rx], v01 = patch[ry][rx + 1];
        float v10 = patch[ry + 1][rx], v11 = patch[ry + 1][rx + 1];
        float wy0 = 1.f - fy, wx0 = 1.f - fx;
        bv = v00 * (wy0 * wx0) + v01 * (wy0 * fx) + v10 * (fy * wx0) +
             v11 * (fy * fx);
      } else {
        bv = bilin_zero(imgA, iy, ix);
      }
      s += feaj[j] * bv;
    }
    scw[cp][lane][wv] = s;
  }
  __syncthreads();

  {
    int cp = t >> 6, Lpl = t & 63;
    float4 v;
    v.x = scw[cp][Lpl][0];
    v.y = scw[cp][Lpl][1];
    v.z = scw[cp][Lpl][2];
    v.w = scw[cp][Lpl][3];
    *(float4*)(cw4 + (size_t)(b * 4 + cp) * HWSZ + p_base + 48 * Lpl) = v;
  }
}

__device__ __forceinline__ float fast_tanh(float x) {
  float ax = fabsf(x);
  float e = __expf(2.f * ax);  // inf for large ax -> t = 1 (correct limit)
  float t = 1.f - 2.f * __builtin_amdgcn_rcpf(e + 1.f);
  return copysignf(t, x);
}

// ---------------------------------------------------------------------------
// Fused cw03 + epilogue + XCD swizzle (p-contiguous chunks per XCD).
// ---------------------------------------------------------------------------
__global__ __launch_bounds__(256, 4) void fused5_kernel(
    const float* __restrict__ fea, const float* __restrict__ conf_img,
    const float* __restrict__ out_off, const float* __restrict__ affc,
    const float* __restrict__ cw4, const float* __restrict__ aff_scale,
    float* __restrict__ out_aff) {
  __shared__ float fpat[32][36];  // 4.6 KB
  int t = threadIdx.x;
  unsigned idx0 =
      (unsigned)xcd_swz(blockIdx.x, Bn * HWSZ / 256) * 256u;
  unsigned b = idx0 / (unsigned)HWSZ;
  unsigned pb0 = idx0 % (unsigned)HWSZ;
  unsigned a = (8u * pb0) / (unsigned)HWSZ;
  unsigned r0f = 8u * pb0 - a * (unsigned)HWSZ;
  int hrf = (int)(r0f / (unsigned)WW);
  int C0 = hrf - 12;
  C0 = (C0 < 0) ? 0 : (C0 > 352 ? 352 : C0);
  C0 &= ~3;

  const float* feab = fea + (size_t)b * 8 * HWSZ;
  const float* imgA = feab + (size_t)a * HWSZ;
  const float* cimg = conf_img + (size_t)b * HWSZ;

  unsigned p = pb0 + t;
  const float* offb = out_off + (size_t)b * 18 * HWSZ;
  const float* ab = affc + (size_t)b * 8 * HWSZ;

  float feaj[8];
#pragma unroll
  for (int j = 0; j < 8; ++j) feaj[j] = feab[j * HWSZ + p];
  float abv[8];
#pragma unroll
  for (int c = 0; c < 8; ++c) abv[c] = ab[c * HWSZ + p];
  float cw4v[4];
#pragma unroll
  for (int c = 0; c < 4; ++c) cw4v[c] = cw4[((size_t)b * 4 + c) * HWSZ + p];

  {
    int rr = t >> 3, cq = t & 7;
    *(float4*)&fpat[rr][4 * cq] =
        *(const float4*)(imgA + (C0 + rr) * WW + C0 + 4 * cq);
  }
  __syncthreads();

  unsigned h = p / (unsigned)WW, wcol = p % (unsigned)WW;
  unsigned r0 = 8u * p - a * (unsigned)HWSZ;
  unsigned hr = r0 / (unsigned)WW;
  float cb = (float)hr;

  float av[8];
#pragma unroll
  for (int c = 0; c < 4; ++c) {
    const float* dyp = offb + (2 * c) * HWSZ + r0;
    const float* dxp = offb + (2 * c + 1) * HWSZ + r0;
    float4 dy0 = *(const float4*)dyp, dy1 = *(const float4*)(dyp + 4);
    float4 dx0 = *(const float4*)dxp, dx1 = *(const float4*)(dxp + 4);
    float dyv[8] = {dy0.x, dy0.y, dy0.z, dy0.w, dy1.x, dy1.y, dy1.z, dy1.w};
    float dxv[8] = {dx0.x, dx0.y, dx0.z, dx0.w, dx1.x, dx1.y, dx1.z, dx1.w};
    float s = 0.f;
#pragma unroll
    for (int j = 0; j < 8; ++j) {
      float iy = dxv[j] + cb, ix = dyv[j] + cb;
      float y0f = floorf(iy), x0f = floorf(ix);
      int y0 = (int)y0f, x0 = (int)x0f;
      float fy = iy - y0f, fx = ix - x0f;
      float bv;
      if (y0 >= C0 && y0 <= C0 + 30 && x0 >= C0 && x0 <= C0 + 30) {
        int ry = y0 - C0, rx = x0 - C0;
        float wy0 = 1.f - fy, wx0 = 1.f - fx;
        bv = fpat[ry][rx] * (wy0 * wx0) + fpat[ry][rx + 1] * (wy0 * fx) +
             fpat[ry + 1][rx] * (fy * wx0) + fpat[ry + 1][rx + 1] * (fy * fx);
      } else {
        bv = bilin_zero(imgA, iy, ix);
      }
      s += feaj[j] * bv;
    }
    av[c] = abv[c] * s;
  }
#pragma unroll
  for (int c = 4; c < 8; ++c) av[c] = abv[c] * cw4v[c - 4];

  float cf[8];
#pragma unroll
  for (int c = 0; c < 8; ++c) {
    int chy = (c < 4) ? 2 * c : 2 * c + 2;
    float dy = offb[chy * HWSZ + p];
    float dx = offb[(chy + 1) * HWSZ + p];
    cf[c] = bilin_zero(cimg, dy + (float)h, dx + (float)wcol);
  }

  float invden = __builtin_amdgcn_rcpf(aff_scale[0] + 1e-8f);
  float tv8[8];
  float asum = 0.f;
#pragma unroll
  for (int c = 0; c < 8; ++c) {
    float tv = fast_tanh(av[c]) * invden * cf[c];
    tv8[c] = tv;
    asum += fabsf(tv);
  }
  asum += 1e-4f;
  asum = fmaxf(asum, 1.f);
  float inv_asum = __builtin_amdgcn_rcpf(asum);
  float ssum = 0.f;
#pragma unroll
  for (int c = 0; c < 8; ++c) {
    tv8[c] *= inv_asum;
    ssum += tv8[c];
  }

  float v9[9];
#pragma unroll
  for (int c = 0; c < 4; ++c) v9[c] = tv8[c];
  v9[4] = 1.f - ssum;
#pragma unroll
  for (int c = 4; c < 8; ++c) v9[c + 1] = tv8[c];

  float mx = v9[0];
#pragma unroll
  for (int i = 1; i < 9; ++i) mx = fmaxf(mx, v9[i]);
  float es = 0.f;
#pragma unroll
  for (int i = 0; i < 9; ++i) {
    v9[i] = __expf(v9[i] - mx);
    es += v9[i];
  }
  float inv = __builtin_amdgcn_rcpf(es);
  float* ob = out_aff + (size_t)b * 9 * HWSZ;
#pragma unroll
  for (int i = 0; i < 9; ++i) ob[i * HWSZ + p] = v9[i] * inv;
}

extern "C" void kernel_launch(void* const* d_in, const int* in_sizes, int n_in,
                              void* d_out, int out_size, void* d_ws,
                              size_t ws_size, hipStream_t stream) {
  const float* guidance = (const float*)d_in[0];
  const float* conf_img = (const float*)d_in[1];
  const float* fea = (const float*)d_in[2];
  const float* Wc = (const float*)d_in[3];
  const float* bc = (const float*)d_in[4];
  const float* ascale = (const float*)d_in[5];

  float* out = (float*)d_out;
  float* out_off = out;                           // (4,18,384,384)
  float* out_aff = out + (size_t)Bn * 18 * HWSZ;  // (4,9,384,384) final output
  // offT3 borrows the aff region of d_out; written by convmfma5, consumed by
  // cw47h before fused5 overwrites the region. 16B-aligned.
  float* offT3f = out_aff;

  float* affc = (float*)d_ws;                        // 4*8*HW floats
  float* cw4 = affc + (size_t)Bn * 8 * HWSZ;         // 4*4*HW floats
  unsigned short* Wbf2 =
      (unsigned short*)(cw4 + (size_t)Bn * 4 * HWSZ);  // 32*160 bf16

  wtrans2_kernel<<<(32 * 160 + 255) / 256, 256, 0, stream>>>(Wc, Wbf2);

  int total = Bn * HWSZ;
  convmfma5_kernel<<<Bn * 12 * 48, 256, 0, stream>>>(guidance, Wbf2, bc,
                                                     out_off, affc, offT3f);
  cw47h_kernel<<<total / 256, 256, 0, stream>>>(fea, (const float4*)offT3f,
                                                cw4);
  fused5_kernel<<<total / 256, 256, 0, stream>>>(fea, conf_img, out_off, affc,
                                                 cw4, ascale, out_aff);
}